// Round 6
// baseline (253.032 us; speedup 1.0000x reference)
//
#include <hip/hip_runtime.h>

#define BQ   8
#define NQ   100
#define HWP  65536
#define TILE 128
#define KS   256         // K columns staged per pass (1KB/row contiguous runs)
#define NCC  32          // chunks per batch -> grid 256 (1 block/CU)
#define NIT  8           // (HWP/NCC)/KS

typedef float  f32x4  __attribute__((ext_vector_type(4)));
typedef __bf16 bf16x8 __attribute__((ext_vector_type(8)));

struct LD { float4 x, y; };

__device__ __forceinline__ uint32_t pk2(float a, float b) {
    // RNE fp32 -> bf16, packed pair
    uint32_t ua = __builtin_bit_cast(uint32_t, a);
    uint32_t ub = __builtin_bit_cast(uint32_t, b);
    ua += 0x7FFFu + ((ua >> 16) & 1u);
    ub += 0x7FFFu + ((ub >> 16) & 1u);
    return (ua >> 16) | (ub & 0xFFFF0000u);
}

__device__ __forceinline__ LD ldrow(const float* __restrict__ base, int row, int pofs) {
    LD r;
    if (row < NQ) {
        const float4* p = (const float4*)(base + (size_t)row * HWP + pofs);
        r.x = p[0];
        r.y = p[1];
    } else {
        r.x = make_float4(0.f, 0.f, 0.f, 0.f);
        r.y = make_float4(0.f, 0.f, 0.f, 0.f);
    }
    return r;
}

// store 8 bf16 (16B) for logical 8-float group g of `row`; slot = g ^ (row&7)
// (R1-proven zero-conflict swizzle; 512B row stride == 0 mod 128B)
__device__ __forceinline__ void st16(unsigned short* buf, int row, int g, const LD& v) {
    const int slot = g ^ (row & 7);
    uint4 u;
    u.x = pk2(v.x.x, v.x.y);
    u.y = pk2(v.x.z, v.x.w);
    u.z = pk2(v.y.x, v.y.y);
    u.w = pk2(v.y.z, v.y.w);
    *(uint4*)(buf + row * KS + slot * 8) = u;
}

__device__ __forceinline__ float sqsum(const LD& v) {
    return v.x.x*v.x.x + v.x.y*v.x.y + v.x.z*v.x.z + v.x.w*v.x.w
         + v.y.x*v.y.x + v.y.y*v.y.y + v.y.z*v.y.z + v.y.w*v.y.w;
}

// One block = (batch, 2048-col chunk). 8 passes; per pass stage 128x256
// A+B tiles (128KB LDS) with 1KB-contiguous per-row reads, then 8 MFMA
// K-steps. Single buffer: per-pass transfer ~26k cy >> latency, so the
// page-run length (not pipelining) is the lever this round.
__global__ __launch_bounds__(512) void matcher_gemm(
    const float* __restrict__ mp, const float* __restrict__ mg,
    float* __restrict__ dotp, float* __restrict__ normA, float* __restrict__ normB)
{
    __shared__ __align__(16) unsigned short ldsA[TILE * KS]; // 64KB
    __shared__ __align__(16) unsigned short ldsB[TILE * KS]; // 64KB

    const int blk  = blockIdx.x;
    const int b    = blk / NCC;
    const int slot = blk - b * NCC;
    const int p0   = slot * NIT * KS;

    const int t    = threadIdx.x;
    const int oct  = t & 7;       // 8-float sub-column within a sweep
    const int row0 = t >> 3;      // 0..63 (also handles row0+64)
    const int lane = t & 63;
    const int w    = t >> 6;      // wave 0..7
    const int wr   = w >> 1;      // 0..3 -> 32-row strip of C
    const int wc   = w & 1;       // 0..1 -> 64-col strip of C

    const float* Ag = mp + (size_t)b * NQ * HWP;
    const float* Bg = mg + (size_t)b * NQ * HWP;

    f32x4 acc[2][4] = {};
    float nA0 = 0.f, nA1 = 0.f, nB0 = 0.f, nB1 = 0.f;

    // staging registers: [row-half][sweep], 4 sweeps x 32B = 1KB/row across octs
    LD aS[2][4], bS[2][4];
    #pragma unroll
    for (int h = 0; h < 2; ++h)
        #pragma unroll
        for (int s = 0; s < 4; ++s) {
            const int pofs = p0 + s * 64 + oct * 8;
            aS[h][s] = ldrow(Ag, row0 + h * 64, pofs);
            bS[h][s] = ldrow(Bg, row0 + h * 64, pofs);
        }

    #pragma unroll 1
    for (int it = 0; it < NIT; ++it) {
        if (it) {  // previous pass's ds_reads done before overwrite (no vmcnt drain)
            asm volatile("s_waitcnt lgkmcnt(0)" ::: "memory");
            __builtin_amdgcn_s_barrier();
        }
        #pragma unroll
        for (int h = 0; h < 2; ++h) {
            const int r = row0 + h * 64;
            #pragma unroll
            for (int s = 0; s < 4; ++s) {
                st16(ldsA, r, s * 8 + oct, aS[h][s]);
                st16(ldsB, r, s * 8 + oct, bS[h][s]);
            }
        }
        #pragma unroll
        for (int s = 0; s < 4; ++s) {
            nA0 += sqsum(aS[0][s]); nA1 += sqsum(aS[1][s]);
            nB0 += sqsum(bS[0][s]); nB1 += sqsum(bS[1][s]);
        }
        if (it + 1 < NIT) {  // next-pass loads: in flight through the compute phase
            #pragma unroll
            for (int h = 0; h < 2; ++h)
                #pragma unroll
                for (int s = 0; s < 4; ++s) {
                    const int pofs = p0 + (it + 1) * KS + s * 64 + oct * 8;
                    aS[h][s] = ldrow(Ag, row0 + h * 64, pofs);
                    bS[h][s] = ldrow(Bg, row0 + h * 64, pofs);
                }
        }
        asm volatile("s_waitcnt lgkmcnt(0)" ::: "memory"); // my ds_writes committed
        __builtin_amdgcn_s_barrier();                      // loads stay in flight

        #pragma unroll
        for (int kk = 0; kk < 8; ++kk) {
            bf16x8 af[2];
            bf16x8 bfv[4];
            #pragma unroll
            for (int m = 0; m < 2; ++m) {
                const int r  = wr * 32 + m * 16 + (lane & 15);
                const int sl = (kk * 4 + (lane >> 4)) ^ (r & 7);
                af[m] = *(const bf16x8*)(ldsA + r * KS + sl * 8);
            }
            #pragma unroll
            for (int n = 0; n < 4; ++n) {
                const int r  = wc * 64 + n * 16 + (lane & 15);
                const int sl = (kk * 4 + (lane >> 4)) ^ (r & 7);
                bfv[n] = *(const bf16x8*)(ldsB + r * KS + sl * 8);
            }
            #pragma unroll
            for (int m = 0; m < 2; ++m)
                #pragma unroll
                for (int n = 0; n < 4; ++n)
                    acc[m][n] = __builtin_amdgcn_mfma_f32_16x16x32_bf16(
                        af[m], bfv[n], acc[m][n], 0, 0, 0);
        }
    }

    // reduce per-row norms across the 8 octant threads (contiguous lanes)
    #pragma unroll
    for (int m = 1; m < 8; m <<= 1) {
        nA0 += __shfl_xor(nA0, m);
        nA1 += __shfl_xor(nA1, m);
        nB0 += __shfl_xor(nB0, m);
        nB1 += __shfl_xor(nB1, m);
    }
    if (oct == 0) {
        float* nap = normA + (size_t)blk * TILE;
        float* nbp = normB + (size_t)blk * TILE;
        nap[row0] = nA0; nap[row0 + 64] = nA1;
        nbp[row0] = nB0; nbp[row0 + 64] = nB1;
    }

    // C/D layout (HW-verified): col = lane&15, row = (lane>>4)*4 + reg
    float* dp = dotp + (size_t)blk * (TILE * TILE);
    const int ccol = lane & 15;
    const int crow = (lane >> 4) * 4;
    #pragma unroll
    for (int m = 0; m < 2; ++m) {
        #pragma unroll
        for (int n = 0; n < 4; ++n) {
            const int gr = wr * 32 + m * 16 + crow;
            const int gc = wc * 64 + n * 16 + ccol;
            #pragma unroll
            for (int j = 0; j < 4; ++j)
                dp[(size_t)(gr + j) * TILE + gc] = acc[m][n][j];
        }
    }
}

// Reduce chunk partials, apply class-agreement term and dice division.
__global__ __launch_bounds__(256) void matcher_finalize(
    const float* __restrict__ y_p, const float* __restrict__ y_gt,
    const float* __restrict__ dotp, const float* __restrict__ normA,
    const float* __restrict__ normB, float* __restrict__ out)
{
    __shared__ float sA[TILE];
    __shared__ float sB[TILE];
    const int b    = blockIdx.x >> 4;
    const int part = blockIdx.x & 15;
    const int t    = threadIdx.x;

    if (t < TILE) {
        float s = 0.f;
        for (int c = 0; c < NCC; ++c) s += normA[(size_t)(b * NCC + c) * TILE + t];
        sA[t] = s;
    } else {
        float s = 0.f;
        for (int c = 0; c < NCC; ++c) s += normB[(size_t)(b * NCC + c) * TILE + (t - TILE)];
        sB[t - TILE] = s;
    }
    __syncthreads();

    for (int i = t; i < 625; i += 256) {
        const int idx = part * 625 + i;           // 0..9999 within batch
        const int n = idx / 100;
        const int k = idx - n * 100;
        float dot = 0.f;
        for (int c = 0; c < NCC; ++c)
            dot += dotp[(size_t)(b * NCC + c) * (TILE * TILE) + n * TILE + k];
        const float yp = y_p[b * NQ + n];
        const float yg = y_gt[b * NQ + k];
        const float t1 = yp * yg + (1.f - yp) * (1.f - yg);
        out[(size_t)b * (NQ * NQ) + idx] = t1 * (2.f * dot) / (sA[n] + sB[k]);
    }
}

extern "C" void kernel_launch(void* const* d_in, const int* in_sizes, int n_in,
                              void* d_out, int out_size, void* d_ws, size_t ws_size,
                              hipStream_t stream)
{
    const float* y_p  = (const float*)d_in[0];
    const float* y_gt = (const float*)d_in[1];
    const float* m_p  = (const float*)d_in[2];
    const float* m_gt = (const float*)d_in[3];
    float* out = (float*)d_out;

    float* dotp  = (float*)d_ws;    // 17 MB at NCC=32 (fits, per R1/R4)
    float* normA = dotp + (size_t)BQ * NCC * TILE * TILE;
    float* normB = normA + (size_t)BQ * NCC * TILE;

    matcher_gemm<<<dim3(BQ * NCC), dim3(512), 0, stream>>>(
        m_p, m_gt, dotp, normA, normB);
    matcher_finalize<<<dim3(BQ * 16), dim3(256), 0, stream>>>(
        y_p, y_gt, dotp, normA, normB, out);
}

// Round 7
// 100.235 us; speedup vs baseline: 2.5244x; 2.5244x over previous
//
#include <hip/hip_runtime.h>

#define BQ   8
#define NQ   100
#define HWP  65536
#define TILE 128
#define KS   256        // fp32 cols staged per pass -> 1KB contiguous per row
#define NCC  32         // chunks per batch -> grid 256
#define NIT  8          // (HWP/NCC)/KS
#define LROW 256        // shorts per LDS row (KS bf16)
#define JR   13         // max rows per wave (rows w+8j, j<13; 100 rows total)

typedef float  f32x4  __attribute__((ext_vector_type(4)));
typedef __bf16 bf16x8 __attribute__((ext_vector_type(8)));

__device__ __forceinline__ uint32_t pk2(float a, float b) {
    // RNE fp32 -> bf16, packed pair
    uint32_t ua = __builtin_bit_cast(uint32_t, a);
    uint32_t ub = __builtin_bit_cast(uint32_t, b);
    ua += 0x7FFFu + ((ua >> 16) & 1u);
    ub += 0x7FFFu + ((ub >> 16) & 1u);
    return (ua >> 16) | (ub & 0xFFFF0000u);
}

// One block = (batch, 2048-col chunk). 8 passes; per pass each WAVE reads
// whole 1KB row-segments (lane l -> float4 at base + l*16B): one DRAM page
// activation per 1KB instead of per 128B (the R1-R5 invariant bottleneck).
// Rows are wave-owned (r = w + 8j) so the LDS write row is wave-uniform.
__global__ __launch_bounds__(512, 2) void matcher_gemm(
    const float* __restrict__ mp, const float* __restrict__ mg,
    float* __restrict__ dotp, float* __restrict__ normA, float* __restrict__ normB)
{
    __shared__ __align__(16) unsigned short ldsA[TILE * LROW]; // 64 KiB
    __shared__ __align__(16) unsigned short ldsB[TILE * LROW]; // 64 KiB

    const int blk  = blockIdx.x;
    const int b    = blk / NCC;
    const int slot = blk - b * NCC;
    const int p0   = slot * (NIT * KS);

    const int t    = threadIdx.x;
    const int lane = t & 63;
    const int w    = t >> 6;      // wave 0..7
    const int wr   = w >> 1;      // 0..3 -> 32-row strip of C
    const int wc   = w & 1;       // 0..1 -> 64-col strip of C

    // zero the padding rows (100..127) once; never rewritten
    for (int i = t; i < (TILE - NQ) * LROW / 8; i += 512) {
        const int off = NQ * LROW + i * 8;
        *(uint4*)(ldsA + off) = uint4{0, 0, 0, 0};
        *(uint4*)(ldsB + off) = uint4{0, 0, 0, 0};
    }

    const float* Ag = mp + (size_t)b * NQ * HWP;
    const float* Bg = mg + (size_t)b * NQ * HWP;

    f32x4 acc[2][4] = {};
    float nsA[JR], nsB[JR];
    #pragma unroll
    for (int j = 0; j < JR; ++j) { nsA[j] = 0.f; nsB[j] = 0.f; }

    // LDS write offset (shorts) within a row: slot = lane>>1 (16B units),
    // XOR'd with row&7 == w&7 (all owned rows share parity w)
    const int wofs = (((lane >> 1) ^ (w & 7)) << 3) + (lane & 1) * 4;

    #pragma unroll 1
    for (int it = 0; it < NIT; ++it) {
        const int cb = p0 + it * KS + lane * 4;   // float col of this lane's float4

        // ---- stage A: 13 wave-wide 1KB row reads, convert, swizzled ds_write
        {
            float4 v[JR];
            #pragma unroll
            for (int j = 0; j < JR; ++j) {
                const int r = w + 8 * j;
                v[j] = (r < NQ) ? *(const float4*)(Ag + (size_t)r * HWP + cb)
                                : make_float4(0.f, 0.f, 0.f, 0.f);
            }
            #pragma unroll
            for (int j = 0; j < JR; ++j) {
                const int r = w + 8 * j;
                if (r < NQ) {
                    nsA[j] += v[j].x*v[j].x + v[j].y*v[j].y + v[j].z*v[j].z + v[j].w*v[j].w;
                    uint2 u;
                    u.x = pk2(v[j].x, v[j].y);
                    u.y = pk2(v[j].z, v[j].w);
                    *(uint2*)(ldsA + r * LROW + wofs) = u;
                }
            }
        }
        // ---- stage B
        {
            float4 v[JR];
            #pragma unroll
            for (int j = 0; j < JR; ++j) {
                const int r = w + 8 * j;
                v[j] = (r < NQ) ? *(const float4*)(Bg + (size_t)r * HWP + cb)
                                : make_float4(0.f, 0.f, 0.f, 0.f);
            }
            #pragma unroll
            for (int j = 0; j < JR; ++j) {
                const int r = w + 8 * j;
                if (r < NQ) {
                    nsB[j] += v[j].x*v[j].x + v[j].y*v[j].y + v[j].z*v[j].z + v[j].w*v[j].w;
                    uint2 u;
                    u.x = pk2(v[j].x, v[j].y);
                    u.y = pk2(v[j].z, v[j].w);
                    *(uint2*)(ldsB + r * LROW + wofs) = u;
                }
            }
        }

        asm volatile("s_waitcnt lgkmcnt(0)" ::: "memory"); // my ds_writes committed
        __builtin_amdgcn_s_barrier();                      // all staging visible

        #pragma unroll
        for (int kk = 0; kk < 8; ++kk) {
            bf16x8 af[2];
            bf16x8 bfv[4];
            #pragma unroll
            for (int m = 0; m < 2; ++m) {
                const int r  = wr * 32 + m * 16 + (lane & 15);
                const int sl = (kk * 4 + (lane >> 4)) ^ (r & 7);
                af[m] = *(const bf16x8*)(ldsA + r * LROW + sl * 8);
            }
            #pragma unroll
            for (int n = 0; n < 4; ++n) {
                const int r  = wc * 64 + n * 16 + (lane & 15);
                const int sl = (kk * 4 + (lane >> 4)) ^ (r & 7);
                bfv[n] = *(const bf16x8*)(ldsB + r * LROW + sl * 8);
            }
            #pragma unroll
            for (int m = 0; m < 2; ++m)
                #pragma unroll
                for (int n = 0; n < 4; ++n)
                    acc[m][n] = __builtin_amdgcn_mfma_f32_16x16x32_bf16(
                        af[m], bfv[n], acc[m][n], 0, 0, 0);
        }

        __builtin_amdgcn_s_barrier();   // all reads done before next-pass writes
    }

    // final per-row norm reduction (once): full-wave shfl tree per owned row
    #pragma unroll
    for (int j = 0; j < JR; ++j) {
        const int r = w + 8 * j;
        float sa = nsA[j], sb = nsB[j];
        #pragma unroll
        for (int m = 1; m < 64; m <<= 1) {
            sa += __shfl_xor(sa, m);
            sb += __shfl_xor(sb, m);
        }
        if (lane == 0 && r < NQ) {
            normA[(size_t)blk * TILE + r] = sa;
            normB[(size_t)blk * TILE + r] = sb;
        }
    }

    // C/D layout (HW-verified): col = lane&15, row = (lane>>4)*4 + reg
    float* dp = dotp + (size_t)blk * (TILE * TILE);
    const int ccol = lane & 15;
    const int crow = (lane >> 4) * 4;
    #pragma unroll
    for (int m = 0; m < 2; ++m) {
        #pragma unroll
        for (int n = 0; n < 4; ++n) {
            const int gr = wr * 32 + m * 16 + crow;
            const int gc = wc * 64 + n * 16 + ccol;
            #pragma unroll
            for (int j = 0; j < 4; ++j)
                dp[(size_t)(gr + j) * TILE + gc] = acc[m][n][j];
        }
    }
}

// Reduce chunk partials, apply class-agreement term and dice division.
// (rows >= 100 of norm arrays are uninitialized ws but provably unused)
__global__ __launch_bounds__(256) void matcher_finalize(
    const float* __restrict__ y_p, const float* __restrict__ y_gt,
    const float* __restrict__ dotp, const float* __restrict__ normA,
    const float* __restrict__ normB, float* __restrict__ out)
{
    __shared__ float sA[TILE];
    __shared__ float sB[TILE];
    const int b    = blockIdx.x >> 4;
    const int part = blockIdx.x & 15;
    const int t    = threadIdx.x;

    if (t < TILE) {
        float s = 0.f;
        for (int c = 0; c < NCC; ++c) s += normA[(size_t)(b * NCC + c) * TILE + t];
        sA[t] = s;
    } else {
        float s = 0.f;
        for (int c = 0; c < NCC; ++c) s += normB[(size_t)(b * NCC + c) * TILE + (t - TILE)];
        sB[t - TILE] = s;
    }
    __syncthreads();

    for (int i = t; i < 625; i += 256) {
        const int idx = part * 625 + i;           // 0..9999 within batch
        const int n = idx / 100;
        const int k = idx - n * 100;
        float dot = 0.f;
        for (int c = 0; c < NCC; ++c)
            dot += dotp[(size_t)(b * NCC + c) * (TILE * TILE) + n * TILE + k];
        const float yp = y_p[b * NQ + n];
        const float yg = y_gt[b * NQ + k];
        const float t1 = yp * yg + (1.f - yp) * (1.f - yg);
        out[(size_t)b * (NQ * NQ) + idx] = t1 * (2.f * dot) / (sA[n] + sB[k]);
    }
}

extern "C" void kernel_launch(void* const* d_in, const int* in_sizes, int n_in,
                              void* d_out, int out_size, void* d_ws, size_t ws_size,
                              hipStream_t stream)
{
    const float* y_p  = (const float*)d_in[0];
    const float* y_gt = (const float*)d_in[1];
    const float* m_p  = (const float*)d_in[2];
    const float* m_gt = (const float*)d_in[3];
    float* out = (float*)d_out;

    float* dotp  = (float*)d_ws;    // 17 MB at NCC=32 (fits, per R1/R4)
    float* normA = dotp + (size_t)BQ * NCC * TILE * TILE;
    float* normB = normA + (size_t)BQ * NCC * TILE;

    matcher_gemm<<<dim3(BQ * NCC), dim3(512), 0, stream>>>(
        m_p, m_gt, dotp, normA, normB);
    matcher_finalize<<<dim3(BQ * 16), dim3(256), 0, stream>>>(
        y_p, y_gt, dotp, normA, normB, out);
}